// Round 1
// baseline (2673.112 us; speedup 1.0000x reference)
//
#include <hip/hip_runtime.h>
#include <math.h>

#define BB 8
#define LAT 128
#define HH 1024
#define KK 294
#define NN 100000
#define EE 1600000
#define NSTEPS 3
// 0.5 * XSIZE
#define XS_HALF 64.0f

// ---------------- decode MLP ----------------

__global__ void k_mlp_in(const float* __restrict__ latent,
                         const float* __restrict__ W0,
                         const float* __restrict__ b0,
                         float* __restrict__ h) {
    int idx = blockIdx.x * blockDim.x + threadIdx.x;   // B*H = 8192
    if (idx >= BB * HH) return;
    int b = idx / HH, i = idx % HH;
    float s = b0[i];
    const float* lat = latent + b * LAT;
    for (int l = 0; l < LAT; ++l) s += lat[l] * W0[l * HH + i];
    h[idx] = fmaxf(s, 0.0f);
}

__global__ void k_mlp_res(const float* __restrict__ hin,
                          const float* __restrict__ W,
                          const float* __restrict__ bias,
                          float* __restrict__ hout) {
    int idx = blockIdx.x * blockDim.x + threadIdx.x;   // 8192
    if (idx >= BB * HH) return;
    int b = idx / HH, i = idx % HH;
    float s = bias[i] + hin[idx];
    const float* hr = hin + b * HH;
    for (int j = 0; j < HH; ++j) s += hr[j] * W[j * HH + i];
    hout[idx] = fmaxf(s, 0.0f);
}

// coef layout: [t][b][k], t in {x,y,z}
__global__ void k_coef(const float* __restrict__ h,
                       const float* __restrict__ Wx, const float* __restrict__ bx,
                       const float* __restrict__ Wy, const float* __restrict__ by,
                       const float* __restrict__ Wz, const float* __restrict__ bz,
                       float* __restrict__ coef) {
    int idx = blockIdx.x * blockDim.x + threadIdx.x;   // 3*B*K = 7056
    if (idx >= 3 * BB * KK) return;
    int t = idx / (BB * KK);
    int r = idx % (BB * KK);
    int b = r / KK, k = r % KK;
    const float* W = (t == 0) ? Wx : ((t == 1) ? Wy : Wz);
    const float* bv = (t == 0) ? bx : ((t == 1) ? by : bz);
    float s = bv[k];
    const float* hr = h + b * HH;
    for (int i = 0; i < HH; ++i) s += hr[i] * W[i * KK + k];
    coef[idx] = s;
}

__global__ void k_reg(const float* __restrict__ coef, float* __restrict__ out_reg) {
    __shared__ float red[256];
    float s = 0.0f;
    for (int i = threadIdx.x; i < 3 * BB * KK; i += 256) {
        float v = coef[i];
        s += v * v;
    }
    red[threadIdx.x] = s;
    __syncthreads();
    for (int off = 128; off > 0; off >>= 1) {
        if ((int)threadIdx.x < off) red[threadIdx.x] += red[threadIdx.x + off];
        __syncthreads();
    }
    if (threadIdx.x == 0) out_reg[0] = 1e-4f * sqrtf(red[0]);
}

// ---------------- flow init: f[n][b][c] = 64 * sum_k c_t[b][k] * Z[k][n] ----------------

__global__ void k_flow_init(const float* __restrict__ coef,
                            const float* __restrict__ Z,
                            float* __restrict__ f) {
    __shared__ float sc[3 * BB * KK];   // 7056 floats = 28.2 KB
    for (int i = threadIdx.x; i < 3 * BB * KK; i += blockDim.x) sc[i] = coef[i];
    __syncthreads();
    int n = blockIdx.x * blockDim.x + threadIdx.x;
    if (n >= NN) return;

    float acc[24];
#pragma unroll
    for (int j = 0; j < 24; ++j) acc[j] = 0.0f;

    for (int k = 0; k < KK; ++k) {
        float z = Z[k * NN + n];
#pragma unroll
        for (int b = 0; b < BB; ++b) {
            acc[b * 3 + 0] += sc[(0 * BB + b) * KK + k] * z;
            acc[b * 3 + 1] += sc[(1 * BB + b) * KK + k] * z;
            acc[b * 3 + 2] += sc[(2 * BB + b) * KK + k] * z;
        }
    }
    float* fr = f + (size_t)n * 24;
#pragma unroll
    for (int j = 0; j < 24; ++j) fr[j] = XS_HALF * acc[j];
}

// ---------------- diffusion ----------------

__global__ void k_deg(const int* __restrict__ ei, const float* __restrict__ ew,
                      float* __restrict__ deg) {
    int e = blockIdx.x * blockDim.x + threadIdx.x;
    if (e >= EE) return;
    atomicAdd(&deg[ei[EE + e]], ew[e]);
}

// one thread per (edge, quad): 6 float4 per edge = 24 floats
__global__ void k_scatter(const int* __restrict__ ei, const float* __restrict__ ew,
                          const float* __restrict__ f, float* __restrict__ agg) {
    int idx = blockIdx.x * blockDim.x + threadIdx.x;   // EE*6 = 9.6M
    if (idx >= EE * 6) return;
    int e = idx / 6, q = idx % 6;
    int s = ei[e];
    int d = ei[EE + e];
    float w = ew[e];
    float4 fv = ((const float4*)f)[(size_t)s * 6 + q];
    float* base = agg + (size_t)d * 24 + q * 4;
    atomicAdd(base + 0, w * fv.x);
    atomicAdd(base + 1, w * fv.y);
    atomicAdd(base + 2, w * fv.z);
    atomicAdd(base + 3, w * fv.w);
}

// f_new = 0.5*f_old + 0.5*agg/deg ; written in place into agg
__global__ void k_combine(const float* __restrict__ fin, float* __restrict__ agg,
                          const float* __restrict__ deg) {
    int idx = blockIdx.x * blockDim.x + threadIdx.x;   // NN*6 = 600000
    if (idx >= NN * 6) return;
    int n = idx / 6;
    float dg = fmaxf(deg[n], 1e-6f);
    float inv = 0.5f / dg;
    float4 a = ((const float4*)agg)[idx];
    float4 fo = ((const float4*)fin)[idx];
    float4 r;
    r.x = 0.5f * fo.x + a.x * inv;
    r.y = 0.5f * fo.y + a.y * inv;
    r.z = 0.5f * fo.z + a.z * inv;
    r.w = 0.5f * fo.w + a.w * inv;
    ((float4*)agg)[idx] = r;
}

// out[b][n][c] = f[n][b][c]
__global__ void k_out(const float* __restrict__ f, float* __restrict__ out) {
    int idx = blockIdx.x * blockDim.x + threadIdx.x;   // B*N*3 = 2.4M
    if (idx >= BB * NN * 3) return;
    int c = idx % 3;
    int r = idx / 3;
    int n = r % NN;
    int b = r / NN;
    out[idx] = f[(size_t)n * 24 + b * 3 + c];
}

extern "C" void kernel_launch(void* const* d_in, const int* in_sizes, int n_in,
                              void* d_out, int out_size, void* d_ws, size_t ws_size,
                              hipStream_t stream) {
    const float* latent = (const float*)d_in[0];
    const float* W0 = (const float*)d_in[1];
    const float* b0 = (const float*)d_in[2];
    const float* W1 = (const float*)d_in[3];
    const float* b1 = (const float*)d_in[4];
    const float* W2 = (const float*)d_in[5];
    const float* b2 = (const float*)d_in[6];
    const float* W3 = (const float*)d_in[7];
    const float* b3 = (const float*)d_in[8];
    const float* Wx = (const float*)d_in[9];
    const float* bx = (const float*)d_in[10];
    const float* Wy = (const float*)d_in[11];
    const float* by = (const float*)d_in[12];
    const float* Wz = (const float*)d_in[13];
    const float* bz = (const float*)d_in[14];
    const float* Z  = (const float*)d_in[15];
    const float* ew = (const float*)d_in[16];
    const int*   ei = (const int*)d_in[17];
    float* out = (float*)d_out;

    char* ws = (char*)d_ws;
    float* h_a  = (float*)(ws + 0);          // 8192 f
    float* h_b  = (float*)(ws + 32768);      // 8192 f
    float* coef = (float*)(ws + 65536);      // 7056 f (pad to 28672 B)
    float* deg  = (float*)(ws + 94208);      // 100000 f (pad to 400128 B)
    float* f0   = (float*)(ws + 494336);     // 2.4M f = 9.6 MB
    float* f1   = (float*)(ws + 10094336);   // 2.4M f = 9.6 MB

    hipMemsetAsync(deg, 0, NN * sizeof(float), stream);

    k_mlp_in<<<32, 256, 0, stream>>>(latent, W0, b0, h_a);
    k_mlp_res<<<32, 256, 0, stream>>>(h_a, W1, b1, h_b);
    k_mlp_res<<<32, 256, 0, stream>>>(h_b, W2, b2, h_a);
    k_mlp_res<<<32, 256, 0, stream>>>(h_a, W3, b3, h_b);
    k_coef<<<(3 * BB * KK + 255) / 256, 256, 0, stream>>>(h_b, Wx, bx, Wy, by, Wz, bz, coef);
    k_reg<<<1, 256, 0, stream>>>(coef, out + (size_t)BB * NN * 3);

    k_deg<<<(EE + 255) / 256, 256, 0, stream>>>(ei, ew, deg);
    k_flow_init<<<(NN + 255) / 256, 256, 0, stream>>>(coef, Z, f0);

    float* fc = f0;
    float* fo = f1;
    for (int s = 0; s < NSTEPS; ++s) {
        hipMemsetAsync(fo, 0, (size_t)NN * 24 * sizeof(float), stream);
        k_scatter<<<(EE * 6 + 255) / 256, 256, 0, stream>>>(ei, ew, fc, fo);
        k_combine<<<(NN * 6 + 255) / 256, 256, 0, stream>>>(fc, fo, deg);
        float* t = fc; fc = fo; fo = t;
    }

    k_out<<<(BB * NN * 3 + 255) / 256, 256, 0, stream>>>(fc, out);
}

// Round 2
// 1132.346 us; speedup vs baseline: 2.3607x; 2.3607x over previous
//
#include <hip/hip_runtime.h>
#include <math.h>

#define BB 8
#define LAT 128
#define HH 1024
#define KK 294
#define NN 100000
#define EE 1600000
#define NSTEPS 3
// 0.5 * XSIZE
#define XS_HALF 64.0f

// ---------------- decode MLP ----------------

__global__ void k_mlp_in(const float* __restrict__ latent,
                         const float* __restrict__ W0,
                         const float* __restrict__ b0,
                         float* __restrict__ h) {
    int idx = blockIdx.x * blockDim.x + threadIdx.x;   // B*H = 8192
    if (idx >= BB * HH) return;
    int b = idx / HH, i = idx % HH;
    float s = b0[i];
    const float* lat = latent + b * LAT;
    for (int l = 0; l < LAT; ++l) s += lat[l] * W0[l * HH + i];
    h[idx] = fmaxf(s, 0.0f);
}

__global__ void k_mlp_res(const float* __restrict__ hin,
                          const float* __restrict__ W,
                          const float* __restrict__ bias,
                          float* __restrict__ hout) {
    int idx = blockIdx.x * blockDim.x + threadIdx.x;   // 8192
    if (idx >= BB * HH) return;
    int b = idx / HH, i = idx % HH;
    float s = bias[i] + hin[idx];
    const float* hr = hin + b * HH;
    for (int j = 0; j < HH; ++j) s += hr[j] * W[j * HH + i];
    hout[idx] = fmaxf(s, 0.0f);
}

// coef layout: [t][b][k], t in {x,y,z}
__global__ void k_coef(const float* __restrict__ h,
                       const float* __restrict__ Wx, const float* __restrict__ bx,
                       const float* __restrict__ Wy, const float* __restrict__ by,
                       const float* __restrict__ Wz, const float* __restrict__ bz,
                       float* __restrict__ coef) {
    int idx = blockIdx.x * blockDim.x + threadIdx.x;   // 3*B*K = 7056
    if (idx >= 3 * BB * KK) return;
    int t = idx / (BB * KK);
    int r = idx % (BB * KK);
    int b = r / KK, k = r % KK;
    const float* W = (t == 0) ? Wx : ((t == 1) ? Wy : Wz);
    const float* bv = (t == 0) ? bx : ((t == 1) ? by : bz);
    float s = bv[k];
    const float* hr = h + b * HH;
    for (int i = 0; i < HH; ++i) s += hr[i] * W[i * KK + k];
    coef[idx] = s;
}

__global__ void k_reg(const float* __restrict__ coef, float* __restrict__ out_reg) {
    __shared__ float red[256];
    float s = 0.0f;
    for (int i = threadIdx.x; i < 3 * BB * KK; i += 256) {
        float v = coef[i];
        s += v * v;
    }
    red[threadIdx.x] = s;
    __syncthreads();
    for (int off = 128; off > 0; off >>= 1) {
        if ((int)threadIdx.x < off) red[threadIdx.x] += red[threadIdx.x + off];
        __syncthreads();
    }
    if (threadIdx.x == 0) out_reg[0] = 1e-4f * sqrtf(red[0]);
}

// ---------------- flow init: f[n][b][c] = 64 * sum_k c_t[b][k] * Z[k][n] ----------------

__global__ void k_flow_init(const float* __restrict__ coef,
                            const float* __restrict__ Z,
                            float* __restrict__ f) {
    __shared__ float sc[3 * BB * KK];   // 7056 floats = 28.2 KB
    for (int i = threadIdx.x; i < 3 * BB * KK; i += blockDim.x) sc[i] = coef[i];
    __syncthreads();
    int n = blockIdx.x * blockDim.x + threadIdx.x;
    if (n >= NN) return;

    float acc[24];
#pragma unroll
    for (int j = 0; j < 24; ++j) acc[j] = 0.0f;

    for (int k = 0; k < KK; ++k) {
        float z = Z[k * NN + n];
#pragma unroll
        for (int b = 0; b < BB; ++b) {
            acc[b * 3 + 0] += sc[(0 * BB + b) * KK + k] * z;
            acc[b * 3 + 1] += sc[(1 * BB + b) * KK + k] * z;
            acc[b * 3 + 2] += sc[(2 * BB + b) * KK + k] * z;
        }
    }
    float* fr = f + (size_t)n * 24;
#pragma unroll
    for (int j = 0; j < 24; ++j) fr[j] = XS_HALF * acc[j];
}

// ---------------- CSR build (by destination) ----------------

__global__ void k_count(const int* __restrict__ ei, int* __restrict__ cnt) {
    int e = blockIdx.x * blockDim.x + threadIdx.x;
    if (e >= EE) return;
    atomicAdd(&cnt[ei[EE + e]], 1);
}

// single-block two-level prefix scan over NN counts -> offs (exclusive), pos (copy)
__global__ void k_scan(const int* __restrict__ cnt, int* __restrict__ offs,
                       int* __restrict__ pos) {
    __shared__ int part[1024];
    const int T = 1024;
    const int CH = (NN + T - 1) / T;   // 98
    int t = threadIdx.x;
    int beg = t * CH;
    int end = beg + CH; if (end > NN) end = NN;
    int s = 0;
    for (int i = beg; i < end; ++i) s += cnt[i];
    part[t] = s;
    __syncthreads();
    // Hillis-Steele inclusive scan
    for (int off = 1; off < T; off <<= 1) {
        int v = (t >= off) ? part[t - off] : 0;
        __syncthreads();
        part[t] += v;
        __syncthreads();
    }
    int run = (t == 0) ? 0 : part[t - 1];
    for (int i = beg; i < end; ++i) {
        offs[i] = run;
        pos[i] = run;
        run += cnt[i];
    }
    if (t == T - 1) offs[NN] = part[T - 1];
}

__global__ void k_fill(const int* __restrict__ ei, const float* __restrict__ ew,
                       int* __restrict__ pos, int* __restrict__ csr_src,
                       float* __restrict__ csr_w) {
    int e = blockIdx.x * blockDim.x + threadIdx.x;
    if (e >= EE) return;
    int src = ei[e];
    int dst = ei[EE + e];
    int p = atomicAdd(&pos[dst], 1);
    csr_src[p] = src;
    csr_w[p] = ew[e];
}

// deg[n] = sum of weights of incoming edges (atomic-free, from CSR)
__global__ void k_degcsr(const int* __restrict__ offs, const float* __restrict__ csr_w,
                         float* __restrict__ deg) {
    int n = blockIdx.x * blockDim.x + threadIdx.x;
    if (n >= NN) return;
    int beg = offs[n], end = offs[n + 1];
    float s = 0.0f;
    for (int i = beg; i < end; ++i) s += csr_w[i];
    deg[n] = s;
}

// ---------------- diffusion step: fused gather + combine ----------------
// 8 threads per node; q in [0,6) handles one float4 of the 24 components.
__global__ void k_gather(const int* __restrict__ offs, const int* __restrict__ csr_src,
                         const float* __restrict__ csr_w, const float* __restrict__ deg,
                         const float* __restrict__ fin, float* __restrict__ fout) {
    int t = blockIdx.x * blockDim.x + threadIdx.x;   // NN*8
    int n = t >> 3;
    int q = t & 7;
    if (n >= NN || q >= 6) return;
    int beg = offs[n], end = offs[n + 1];
    const float4* f4 = (const float4*)fin;
    float4 acc = make_float4(0.f, 0.f, 0.f, 0.f);
    for (int i = beg; i < end; ++i) {
        int s = csr_src[i];
        float w = csr_w[i];
        float4 fv = f4[(size_t)s * 6 + q];
        acc.x += w * fv.x;
        acc.y += w * fv.y;
        acc.z += w * fv.z;
        acc.w += w * fv.w;
    }
    float dg = fmaxf(deg[n], 1e-6f);
    float inv = 0.5f / dg;
    float4 fo = f4[(size_t)n * 6 + q];
    float4 r;
    r.x = 0.5f * fo.x + inv * acc.x;
    r.y = 0.5f * fo.y + inv * acc.y;
    r.z = 0.5f * fo.z + inv * acc.z;
    r.w = 0.5f * fo.w + inv * acc.w;
    ((float4*)fout)[(size_t)n * 6 + q] = r;
}

// out[b][n][c] = f[n][b][c]
__global__ void k_out(const float* __restrict__ f, float* __restrict__ out) {
    int idx = blockIdx.x * blockDim.x + threadIdx.x;   // B*N*3 = 2.4M
    if (idx >= BB * NN * 3) return;
    int c = idx % 3;
    int r = idx / 3;
    int n = r % NN;
    int b = r / NN;
    out[idx] = f[(size_t)n * 24 + b * 3 + c];
}

extern "C" void kernel_launch(void* const* d_in, const int* in_sizes, int n_in,
                              void* d_out, int out_size, void* d_ws, size_t ws_size,
                              hipStream_t stream) {
    const float* latent = (const float*)d_in[0];
    const float* W0 = (const float*)d_in[1];
    const float* b0 = (const float*)d_in[2];
    const float* W1 = (const float*)d_in[3];
    const float* b1 = (const float*)d_in[4];
    const float* W2 = (const float*)d_in[5];
    const float* b2 = (const float*)d_in[6];
    const float* W3 = (const float*)d_in[7];
    const float* b3 = (const float*)d_in[8];
    const float* Wx = (const float*)d_in[9];
    const float* bx = (const float*)d_in[10];
    const float* Wy = (const float*)d_in[11];
    const float* by = (const float*)d_in[12];
    const float* Wz = (const float*)d_in[13];
    const float* bz = (const float*)d_in[14];
    const float* Z  = (const float*)d_in[15];
    const float* ew = (const float*)d_in[16];
    const int*   ei = (const int*)d_in[17];
    float* out = (float*)d_out;

    char* ws = (char*)d_ws;
    float* h_a     = (float*)(ws + 0);           // 8192 f
    float* h_b     = (float*)(ws + 32768);       // 8192 f
    float* coef    = (float*)(ws + 65536);       // 7056 f
    float* deg     = (float*)(ws + 94336);       // 100000 f
    int*   cnt     = (int*)  (ws + 494464);      // 100000 i
    int*   offs    = (int*)  (ws + 894592);      // 100001 i
    int*   pos     = (int*)  (ws + 1294720);     // 100000 i
    int*   csr_src = (int*)  (ws + 1694848);     // 1.6M i
    float* csr_w   = (float*)(ws + 8094848);     // 1.6M f
    float* f0      = (float*)(ws + 14494848);    // 2.4M f = 9.6 MB
    float* f1      = (float*)(ws + 24094848);    // 2.4M f = 9.6 MB

    // ---- CSR build (independent of MLP) ----
    hipMemsetAsync(cnt, 0, NN * sizeof(int), stream);
    k_count<<<(EE + 255) / 256, 256, 0, stream>>>(ei, cnt);
    k_scan<<<1, 1024, 0, stream>>>(cnt, offs, pos);
    k_fill<<<(EE + 255) / 256, 256, 0, stream>>>(ei, ew, pos, csr_src, csr_w);
    k_degcsr<<<(NN + 255) / 256, 256, 0, stream>>>(offs, csr_w, deg);

    // ---- decode MLP ----
    k_mlp_in<<<32, 256, 0, stream>>>(latent, W0, b0, h_a);
    k_mlp_res<<<32, 256, 0, stream>>>(h_a, W1, b1, h_b);
    k_mlp_res<<<32, 256, 0, stream>>>(h_b, W2, b2, h_a);
    k_mlp_res<<<32, 256, 0, stream>>>(h_a, W3, b3, h_b);
    k_coef<<<(3 * BB * KK + 255) / 256, 256, 0, stream>>>(h_b, Wx, bx, Wy, by, Wz, bz, coef);
    k_reg<<<1, 256, 0, stream>>>(coef, out + (size_t)BB * NN * 3);

    // ---- flow init ----
    k_flow_init<<<(NN + 255) / 256, 256, 0, stream>>>(coef, Z, f0);

    // ---- diffusion: 3 fused gather+combine steps ----
    float* fc = f0;
    float* fo = f1;
    for (int s = 0; s < NSTEPS; ++s) {
        k_gather<<<(NN * 8 + 255) / 256, 256, 0, stream>>>(offs, csr_src, csr_w, deg, fc, fo);
        float* t = fc; fc = fo; fo = t;
    }

    k_out<<<(BB * NN * 3 + 255) / 256, 256, 0, stream>>>(fc, out);
}

// Round 3
// 917.274 us; speedup vs baseline: 2.9142x; 1.2345x over previous
//
#include <hip/hip_runtime.h>
#include <math.h>

#define BB 8
#define LAT 128
#define HH 1024
#define KK 294
#define NN 100000
#define EE 1600000
#define NSTEPS 3
// 0.5 * XSIZE
#define XS_HALF 64.0f

#define NB 391   // ceil(NN/256)

// ---------------- decode MLP ----------------

__global__ void k_mlp_in(const float* __restrict__ latent,
                         const float* __restrict__ W0,
                         const float* __restrict__ b0,
                         float* __restrict__ h) {
    int idx = blockIdx.x * blockDim.x + threadIdx.x;   // B*H = 8192
    if (idx >= BB * HH) return;
    int b = idx / HH, i = idx % HH;
    float s = b0[i];
    const float* lat = latent + b * LAT;
    for (int l = 0; l < LAT; ++l) s += lat[l] * W0[l * HH + i];
    h[idx] = fmaxf(s, 0.0f);
}

__global__ void k_mlp_res(const float* __restrict__ hin,
                          const float* __restrict__ W,
                          const float* __restrict__ bias,
                          float* __restrict__ hout) {
    int idx = blockIdx.x * blockDim.x + threadIdx.x;   // 8192
    if (idx >= BB * HH) return;
    int b = idx / HH, i = idx % HH;
    float s = bias[i] + hin[idx];
    const float* hr = hin + b * HH;
    for (int j = 0; j < HH; ++j) s += hr[j] * W[j * HH + i];
    hout[idx] = fmaxf(s, 0.0f);
}

// coef layout: [t][b][k], t in {x,y,z}
__global__ void k_coef(const float* __restrict__ h,
                       const float* __restrict__ Wx, const float* __restrict__ bx,
                       const float* __restrict__ Wy, const float* __restrict__ by,
                       const float* __restrict__ Wz, const float* __restrict__ bz,
                       float* __restrict__ coef) {
    int idx = blockIdx.x * blockDim.x + threadIdx.x;   // 3*B*K = 7056
    if (idx >= 3 * BB * KK) return;
    int t = idx / (BB * KK);
    int r = idx % (BB * KK);
    int b = r / KK, k = r % KK;
    const float* W = (t == 0) ? Wx : ((t == 1) ? Wy : Wz);
    const float* bv = (t == 0) ? bx : ((t == 1) ? by : bz);
    float s = bv[k];
    const float* hr = h + b * HH;
    for (int i = 0; i < HH; ++i) s += hr[i] * W[i * KK + k];
    coef[idx] = s;
}

__global__ void k_reg(const float* __restrict__ coef, float* __restrict__ out_reg) {
    __shared__ float red[256];
    float s = 0.0f;
    for (int i = threadIdx.x; i < 3 * BB * KK; i += 256) {
        float v = coef[i];
        s += v * v;
    }
    red[threadIdx.x] = s;
    __syncthreads();
    for (int off = 128; off > 0; off >>= 1) {
        if ((int)threadIdx.x < off) red[threadIdx.x] += red[threadIdx.x + off];
        __syncthreads();
    }
    if (threadIdx.x == 0) out_reg[0] = 1e-4f * sqrtf(red[0]);
}

// ---------------- flow init: f[n][b][c] = 64 * sum_k c_t[b][k] * Z[k][n] ----------------

__global__ void k_flow_init(const float* __restrict__ coef,
                            const float* __restrict__ Z,
                            float* __restrict__ f) {
    __shared__ float sc[3 * BB * KK];   // 7056 floats = 28.2 KB
    for (int i = threadIdx.x; i < 3 * BB * KK; i += blockDim.x) sc[i] = coef[i];
    __syncthreads();
    int n = blockIdx.x * blockDim.x + threadIdx.x;
    if (n >= NN) return;

    float acc[24];
#pragma unroll
    for (int j = 0; j < 24; ++j) acc[j] = 0.0f;

    for (int k = 0; k < KK; ++k) {
        float z = Z[k * NN + n];
#pragma unroll
        for (int b = 0; b < BB; ++b) {
            acc[b * 3 + 0] += sc[(0 * BB + b) * KK + k] * z;
            acc[b * 3 + 1] += sc[(1 * BB + b) * KK + k] * z;
            acc[b * 3 + 2] += sc[(2 * BB + b) * KK + k] * z;
        }
    }
    float* fr = f + (size_t)n * 24;
#pragma unroll
    for (int j = 0; j < 24; ++j) fr[j] = XS_HALF * acc[j];
}

// ---------------- CSR build (by destination) ----------------

__global__ void k_count(const int* __restrict__ ei, int* __restrict__ cnt) {
    int e = blockIdx.x * blockDim.x + threadIdx.x;
    if (e >= EE) return;
    atomicAdd(&cnt[ei[EE + e]], 1);
}

// Phase 1: per-block sums of cnt (391 blocks x 256)
__global__ void k_bsum(const int* __restrict__ cnt, int* __restrict__ bsum) {
    __shared__ int red[256];
    int i = blockIdx.x * 256 + threadIdx.x;
    red[threadIdx.x] = (i < NN) ? cnt[i] : 0;
    __syncthreads();
    for (int off = 128; off > 0; off >>= 1) {
        if ((int)threadIdx.x < off) red[threadIdx.x] += red[threadIdx.x + off];
        __syncthreads();
    }
    if (threadIdx.x == 0) bsum[blockIdx.x] = red[0];
}

// Phase 2: single small block scans the 391 block sums -> exclusive bpre, total -> offs[NN]
__global__ void k_bscan(const int* __restrict__ bsum, int* __restrict__ bpre,
                        int* __restrict__ offs) {
    __shared__ int part[512];
    int t = threadIdx.x;
    part[t] = (t < NB) ? bsum[t] : 0;
    __syncthreads();
    for (int off = 1; off < 512; off <<= 1) {
        int v = (t >= off) ? part[t - off] : 0;
        __syncthreads();
        part[t] += v;
        __syncthreads();
    }
    if (t < NB) bpre[t] = (t == 0) ? 0 : part[t - 1];
    if (t == NB - 1) offs[NN] = part[t];
}

// Phase 3: per-block exclusive scan + block prefix -> offs, pos
__global__ void k_offs(const int* __restrict__ cnt, const int* __restrict__ bpre,
                       int* __restrict__ offs, int* __restrict__ pos) {
    __shared__ int part[256];
    int t = threadIdx.x;
    int i = blockIdx.x * 256 + t;
    int v = (i < NN) ? cnt[i] : 0;
    part[t] = v;
    __syncthreads();
    for (int off = 1; off < 256; off <<= 1) {
        int u = (t >= off) ? part[t - off] : 0;
        __syncthreads();
        part[t] += u;
        __syncthreads();
    }
    if (i < NN) {
        int ex = bpre[blockIdx.x] + part[t] - v;   // exclusive
        offs[i] = ex;
        pos[i] = ex;
    }
}

__global__ void k_fill(const int* __restrict__ ei, const float* __restrict__ ew,
                       int* __restrict__ pos, int* __restrict__ csr_src,
                       float* __restrict__ csr_w) {
    int e = blockIdx.x * blockDim.x + threadIdx.x;
    if (e >= EE) return;
    int src = ei[e];
    int dst = ei[EE + e];
    int p = atomicAdd(&pos[dst], 1);
    csr_src[p] = src;
    csr_w[p] = ew[e];
}

// deg[n] = sum of weights of incoming edges (atomic-free, from CSR)
__global__ void k_degcsr(const int* __restrict__ offs, const float* __restrict__ csr_w,
                         float* __restrict__ deg) {
    int n = blockIdx.x * blockDim.x + threadIdx.x;
    if (n >= NN) return;
    int beg = offs[n], end = offs[n + 1];
    float s = 0.0f;
    for (int i = beg; i < end; ++i) s += csr_w[i];
    deg[n] = s;
}

// ---------------- diffusion step: fused gather + combine ----------------
// 8 threads per node; q in [0,6) handles one float4 of the 24 components.
__global__ void k_gather(const int* __restrict__ offs, const int* __restrict__ csr_src,
                         const float* __restrict__ csr_w, const float* __restrict__ deg,
                         const float* __restrict__ fin, float* __restrict__ fout) {
    int t = blockIdx.x * blockDim.x + threadIdx.x;   // NN*8
    int n = t >> 3;
    int q = t & 7;
    if (n >= NN || q >= 6) return;
    int beg = offs[n], end = offs[n + 1];
    const float4* f4 = (const float4*)fin;
    float4 acc = make_float4(0.f, 0.f, 0.f, 0.f);
    for (int i = beg; i < end; ++i) {
        int s = csr_src[i];
        float w = csr_w[i];
        float4 fv = f4[(size_t)s * 6 + q];
        acc.x += w * fv.x;
        acc.y += w * fv.y;
        acc.z += w * fv.z;
        acc.w += w * fv.w;
    }
    float dg = fmaxf(deg[n], 1e-6f);
    float inv = 0.5f / dg;
    float4 fo = f4[(size_t)n * 6 + q];
    float4 r;
    r.x = 0.5f * fo.x + inv * acc.x;
    r.y = 0.5f * fo.y + inv * acc.y;
    r.z = 0.5f * fo.z + inv * acc.z;
    r.w = 0.5f * fo.w + inv * acc.w;
    ((float4*)fout)[(size_t)n * 6 + q] = r;
}

// out[b][n][c] = f[n][b][c]
__global__ void k_out(const float* __restrict__ f, float* __restrict__ out) {
    int idx = blockIdx.x * blockDim.x + threadIdx.x;   // B*N*3 = 2.4M
    if (idx >= BB * NN * 3) return;
    int c = idx % 3;
    int r = idx / 3;
    int n = r % NN;
    int b = r / NN;
    out[idx] = f[(size_t)n * 24 + b * 3 + c];
}

extern "C" void kernel_launch(void* const* d_in, const int* in_sizes, int n_in,
                              void* d_out, int out_size, void* d_ws, size_t ws_size,
                              hipStream_t stream) {
    const float* latent = (const float*)d_in[0];
    const float* W0 = (const float*)d_in[1];
    const float* b0 = (const float*)d_in[2];
    const float* W1 = (const float*)d_in[3];
    const float* b1 = (const float*)d_in[4];
    const float* W2 = (const float*)d_in[5];
    const float* b2 = (const float*)d_in[6];
    const float* W3 = (const float*)d_in[7];
    const float* b3 = (const float*)d_in[8];
    const float* Wx = (const float*)d_in[9];
    const float* bx = (const float*)d_in[10];
    const float* Wy = (const float*)d_in[11];
    const float* by = (const float*)d_in[12];
    const float* Wz = (const float*)d_in[13];
    const float* bz = (const float*)d_in[14];
    const float* Z  = (const float*)d_in[15];
    const float* ew = (const float*)d_in[16];
    const int*   ei = (const int*)d_in[17];
    float* out = (float*)d_out;

    char* ws = (char*)d_ws;
    float* h_a     = (float*)(ws + 0);           // 8192 f
    float* h_b     = (float*)(ws + 32768);       // 8192 f
    float* coef    = (float*)(ws + 65536);       // 7056 f
    float* deg     = (float*)(ws + 94336);       // 100000 f
    int*   cnt     = (int*)  (ws + 494464);      // 100000 i
    int*   offs    = (int*)  (ws + 894592);      // 100001 i
    int*   pos     = (int*)  (ws + 1294720);     // 100000 i
    int*   bsum    = (int*)  (ws + 1694848);     // 391 i
    int*   bpre    = (int*)  (ws + 1696448);     // 391 i
    int*   csr_src = (int*)  (ws + 1698048);     // 1.6M i
    float* csr_w   = (float*)(ws + 8098048);     // 1.6M f
    float* f0      = (float*)(ws + 14498048);    // 2.4M f = 9.6 MB
    float* f1      = (float*)(ws + 24098048);    // 2.4M f = 9.6 MB

    // ---- CSR build (independent of MLP) ----
    hipMemsetAsync(cnt, 0, NN * sizeof(int), stream);
    k_count<<<(EE + 255) / 256, 256, 0, stream>>>(ei, cnt);
    k_bsum<<<NB, 256, 0, stream>>>(cnt, bsum);
    k_bscan<<<1, 512, 0, stream>>>(bsum, bpre, offs);
    k_offs<<<NB, 256, 0, stream>>>(cnt, bpre, offs, pos);
    k_fill<<<(EE + 255) / 256, 256, 0, stream>>>(ei, ew, pos, csr_src, csr_w);
    k_degcsr<<<(NN + 255) / 256, 256, 0, stream>>>(offs, csr_w, deg);

    // ---- decode MLP ----
    k_mlp_in<<<32, 256, 0, stream>>>(latent, W0, b0, h_a);
    k_mlp_res<<<32, 256, 0, stream>>>(h_a, W1, b1, h_b);
    k_mlp_res<<<32, 256, 0, stream>>>(h_b, W2, b2, h_a);
    k_mlp_res<<<32, 256, 0, stream>>>(h_a, W3, b3, h_b);
    k_coef<<<(3 * BB * KK + 255) / 256, 256, 0, stream>>>(h_b, Wx, bx, Wy, by, Wz, bz, coef);
    k_reg<<<1, 256, 0, stream>>>(coef, out + (size_t)BB * NN * 3);

    // ---- flow init ----
    k_flow_init<<<(NN + 255) / 256, 256, 0, stream>>>(coef, Z, f0);

    // ---- diffusion: 3 fused gather+combine steps ----
    float* fc = f0;
    float* fo = f1;
    for (int s = 0; s < NSTEPS; ++s) {
        k_gather<<<(NN * 8 + 255) / 256, 256, 0, stream>>>(offs, csr_src, csr_w, deg, fc, fo);
        float* t = fc; fc = fo; fo = t;
    }

    k_out<<<(BB * NN * 3 + 255) / 256, 256, 0, stream>>>(fc, out);
}

// Round 4
// 674.531 us; speedup vs baseline: 3.9629x; 1.3599x over previous
//
#include <hip/hip_runtime.h>
#include <math.h>

#define BB 8
#define LAT 128
#define HH 1024
#define KK 294
#define NN 100000
#define EE 1600000
#define NSTEPS 3
#define XS_HALF 64.0f

#define NB 391      // ceil(NN/256)
#define FS 4        // flow_init k-splits
#define FCH 74      // ceil(294/4)
#define CS 8        // coef j-splits (128 each)
#define COB 28      // ceil(7056/256)

// ---------------- decode MLP: split-K GEMM ----------------
// out_partial[bs][b][i] = sum_{j in split bs} hin[b][j] * W[j][i]
// grid = 16 i-tiles * (jdim/64) splits; block = 256 (4 waves; wave jg handles 16 j's)
__global__ void k_mlp_part(const float* __restrict__ hin, const float* __restrict__ W,
                           float* __restrict__ part, int jdim) {
    int it = blockIdx.x & 15;
    int bs = blockIdx.x >> 4;
    int tx = threadIdx.x;
    int il = tx & 63;
    int jg = tx >> 6;          // wave id 0..3
    int i = it * 64 + il;
    int j0 = bs * 64;

    __shared__ float hs[8 * 64];
    for (int u = tx; u < 512; u += 256) {
        int b = u >> 6, lj = u & 63;
        hs[u] = hin[b * jdim + j0 + lj];
    }
    __syncthreads();

    float acc[8];
#pragma unroll
    for (int b = 0; b < 8; ++b) acc[b] = 0.0f;
#pragma unroll
    for (int jj = 0; jj < 16; ++jj) {
        int lj = jg * 16 + jj;
        float w = W[(size_t)(j0 + lj) * HH + i];
#pragma unroll
        for (int b = 0; b < 8; ++b) acc[b] += hs[b * 64 + lj] * w;
    }

    __shared__ float red[4][8][64];
#pragma unroll
    for (int b = 0; b < 8; ++b) red[jg][b][il] = acc[b];
    __syncthreads();
    for (int u = tx; u < 512; u += 256) {
        int b = u >> 6, ii = u & 63;
        float s = red[0][b][ii] + red[1][b][ii] + red[2][b][ii] + red[3][b][ii];
        part[(size_t)bs * 8192 + b * HH + it * 64 + ii] = s;
    }
}

// hout[b][i] = relu(bias[i] + resid[b][i] + sum_bs part[bs][b][i])
__global__ void k_mlp_comb(const float* __restrict__ part, int nsplit,
                           const float* __restrict__ resid,
                           const float* __restrict__ bias,
                           float* __restrict__ hout) {
    int idx = blockIdx.x * 256 + threadIdx.x;   // 8192
    if (idx >= BB * HH) return;
    int i = idx & (HH - 1);
    float s = bias[i];
    if (resid) s += resid[idx];
    for (int bs = 0; bs < nsplit; ++bs) s += part[(size_t)bs * 8192 + idx];
    hout[idx] = fmaxf(s, 0.0f);
}

// ---------------- coef projection: split-K ----------------
__global__ void k_coef_part(const float* __restrict__ h,
                            const float* __restrict__ Wx,
                            const float* __restrict__ Wy,
                            const float* __restrict__ Wz,
                            float* __restrict__ cpart) {
    int s = blockIdx.x / COB;
    int blk = blockIdx.x % COB;
    int o = blk * 256 + threadIdx.x;
    if (o >= 3 * BB * KK) return;
    int t = o / (BB * KK);
    int r = o % (BB * KK);
    int b = r / KK, k = r % KK;
    const float* W = (t == 0) ? Wx : ((t == 1) ? Wy : Wz);
    const float* hr = h + b * HH;
    int j0 = s * 128;
    float acc = 0.0f;
#pragma unroll 8
    for (int j = 0; j < 128; ++j) acc += hr[j0 + j] * W[(size_t)(j0 + j) * KK + k];
    cpart[(size_t)s * 7056 + o] = acc;
}

__global__ void k_coef_comb(const float* __restrict__ cpart,
                            const float* __restrict__ bx,
                            const float* __restrict__ by,
                            const float* __restrict__ bz,
                            float* __restrict__ coef) {
    int o = blockIdx.x * 256 + threadIdx.x;
    if (o >= 3 * BB * KK) return;
    int t = o / (BB * KK);
    int k = o % KK;
    float s = ((t == 0) ? bx : ((t == 1) ? by : bz))[k];
#pragma unroll
    for (int i = 0; i < CS; ++i) s += cpart[(size_t)i * 7056 + o];
    coef[o] = s;
}

__global__ void k_reg(const float* __restrict__ coef, float* __restrict__ out_reg) {
    __shared__ float red[256];
    float s = 0.0f;
    for (int i = threadIdx.x; i < 3 * BB * KK; i += 256) {
        float v = coef[i];
        s += v * v;
    }
    red[threadIdx.x] = s;
    __syncthreads();
    for (int off = 128; off > 0; off >>= 1) {
        if ((int)threadIdx.x < off) red[threadIdx.x] += red[threadIdx.x + off];
        __syncthreads();
    }
    if (threadIdx.x == 0) out_reg[0] = 1e-4f * sqrtf(red[0]);
}

// ---------------- flow init, k-split ----------------
// fpart[s][n*24+j] = sum_{k in chunk s} coef[j][k] * Z[k][n]   (j = b*3+c order via t*8+b)
__global__ void k_flow_part(const float* __restrict__ coef,
                            const float* __restrict__ Z,
                            float* __restrict__ fpart) {
    int s = blockIdx.x / NB;
    int blk = blockIdx.x % NB;
    int ks = s * FCH;

    __shared__ float sc[24 * FCH];
    for (int u = threadIdx.x; u < 24 * FCH; u += 256) {
        int j = u / FCH, kk = u % FCH;
        int k = ks + kk;
        sc[u] = (k < KK) ? coef[j * KK + k] : 0.0f;
    }
    __syncthreads();

    int n = blk * 256 + threadIdx.x;
    if (n >= NN) return;

    float acc[24];
#pragma unroll
    for (int j = 0; j < 24; ++j) acc[j] = 0.0f;

#pragma unroll 2
    for (int kk = 0; kk < FCH; ++kk) {
        int k = ks + kk;
        int kz = (k < KK) ? k : (KK - 1);
        float z = Z[(size_t)kz * NN + n];
#pragma unroll
        for (int b = 0; b < 8; ++b) {
            acc[b * 3 + 0] += sc[(0 * BB + b) * FCH + kk] * z;
            acc[b * 3 + 1] += sc[(1 * BB + b) * FCH + kk] * z;
            acc[b * 3 + 2] += sc[(2 * BB + b) * FCH + kk] * z;
        }
    }
    float* fr = fpart + (size_t)s * (NN * 24) + (size_t)n * 24;
#pragma unroll
    for (int j = 0; j < 24; ++j) fr[j] = acc[j];
}

// f0 = 64 * (p0+p1+p2+p3), in place into partial slot 0
__global__ void k_flow_comb(float* __restrict__ fpart) {
    int idx = blockIdx.x * 256 + threadIdx.x;   // NN*6 float4s
    if (idx >= NN * 6) return;
    float4* p0 = (float4*)fpart;
    const float4* p1 = p0 + NN * 6;
    const float4* p2 = p1 + NN * 6;
    const float4* p3 = p2 + NN * 6;
    float4 a = p0[idx], b = p1[idx], c = p2[idx], d = p3[idx];
    float4 r;
    r.x = XS_HALF * (a.x + b.x + c.x + d.x);
    r.y = XS_HALF * (a.y + b.y + c.y + d.y);
    r.z = XS_HALF * (a.z + b.z + c.z + d.z);
    r.w = XS_HALF * (a.w + b.w + c.w + d.w);
    p0[idx] = r;
}

// ---------------- CSR build (by destination) ----------------

__global__ void k_count(const int* __restrict__ ei, int* __restrict__ cnt) {
    int e = blockIdx.x * blockDim.x + threadIdx.x;
    if (e >= EE) return;
    atomicAdd(&cnt[ei[EE + e]], 1);
}

__global__ void k_bsum(const int* __restrict__ cnt, int* __restrict__ bsum) {
    __shared__ int red[256];
    int i = blockIdx.x * 256 + threadIdx.x;
    red[threadIdx.x] = (i < NN) ? cnt[i] : 0;
    __syncthreads();
    for (int off = 128; off > 0; off >>= 1) {
        if ((int)threadIdx.x < off) red[threadIdx.x] += red[threadIdx.x + off];
        __syncthreads();
    }
    if (threadIdx.x == 0) bsum[blockIdx.x] = red[0];
}

__global__ void k_bscan(const int* __restrict__ bsum, int* __restrict__ bpre,
                        int* __restrict__ offs) {
    __shared__ int part[512];
    int t = threadIdx.x;
    part[t] = (t < NB) ? bsum[t] : 0;
    __syncthreads();
    for (int off = 1; off < 512; off <<= 1) {
        int v = (t >= off) ? part[t - off] : 0;
        __syncthreads();
        part[t] += v;
        __syncthreads();
    }
    if (t < NB) bpre[t] = (t == 0) ? 0 : part[t - 1];
    if (t == NB - 1) offs[NN] = part[t];
}

__global__ void k_offs(const int* __restrict__ cnt, const int* __restrict__ bpre,
                       int* __restrict__ offs, int* __restrict__ pos) {
    __shared__ int part[256];
    int t = threadIdx.x;
    int i = blockIdx.x * 256 + t;
    int v = (i < NN) ? cnt[i] : 0;
    part[t] = v;
    __syncthreads();
    for (int off = 1; off < 256; off <<= 1) {
        int u = (t >= off) ? part[t - off] : 0;
        __syncthreads();
        part[t] += u;
        __syncthreads();
    }
    if (i < NN) {
        int ex = bpre[blockIdx.x] + part[t] - v;
        offs[i] = ex;
        pos[i] = ex;
    }
}

__global__ void k_fill(const int* __restrict__ ei, const float* __restrict__ ew,
                       int* __restrict__ pos, int* __restrict__ csr_src,
                       float* __restrict__ csr_w) {
    int e = blockIdx.x * blockDim.x + threadIdx.x;
    if (e >= EE) return;
    int src = ei[e];
    int dst = ei[EE + e];
    int p = atomicAdd(&pos[dst], 1);
    csr_src[p] = src;
    csr_w[p] = ew[e];
}

__global__ void k_degcsr(const int* __restrict__ offs, const float* __restrict__ csr_w,
                         float* __restrict__ deg) {
    int n = blockIdx.x * blockDim.x + threadIdx.x;
    if (n >= NN) return;
    int beg = offs[n], end = offs[n + 1];
    float s = 0.0f;
    for (int i = beg; i < end; ++i) s += csr_w[i];
    deg[n] = s;
}

// ---------------- diffusion step: fused gather + combine ----------------
// 6 threads per node; q in [0,6) handles one float4 of the 24 components.
__global__ void k_gather(const int* __restrict__ offs, const int* __restrict__ csr_src,
                         const float* __restrict__ csr_w, const float* __restrict__ deg,
                         const float* __restrict__ fin, float* __restrict__ fout) {
    int idx = blockIdx.x * 256 + threadIdx.x;   // NN*6
    if (idx >= NN * 6) return;
    int n = idx / 6;
    int q = idx - n * 6;
    int beg = offs[n], end = offs[n + 1];
    const float4* f4 = (const float4*)fin;
    float4 acc = make_float4(0.f, 0.f, 0.f, 0.f);
    for (int i = beg; i < end; ++i) {
        int s = csr_src[i];
        float w = csr_w[i];
        float4 fv = f4[(size_t)s * 6 + q];
        acc.x += w * fv.x;
        acc.y += w * fv.y;
        acc.z += w * fv.z;
        acc.w += w * fv.w;
    }
    float dg = fmaxf(deg[n], 1e-6f);
    float inv = 0.5f / dg;
    float4 fo = f4[(size_t)n * 6 + q];
    float4 r;
    r.x = 0.5f * fo.x + inv * acc.x;
    r.y = 0.5f * fo.y + inv * acc.y;
    r.z = 0.5f * fo.z + inv * acc.z;
    r.w = 0.5f * fo.w + inv * acc.w;
    ((float4*)fout)[(size_t)n * 6 + q] = r;
}

// out[b][n][c] = f[n][b][c]
__global__ void k_out(const float* __restrict__ f, float* __restrict__ out) {
    int idx = blockIdx.x * blockDim.x + threadIdx.x;   // B*N*3 = 2.4M
    if (idx >= BB * NN * 3) return;
    int c = idx % 3;
    int r = idx / 3;
    int n = r % NN;
    int b = r / NN;
    out[idx] = f[(size_t)n * 24 + b * 3 + c];
}

extern "C" void kernel_launch(void* const* d_in, const int* in_sizes, int n_in,
                              void* d_out, int out_size, void* d_ws, size_t ws_size,
                              hipStream_t stream) {
    const float* latent = (const float*)d_in[0];
    const float* W0 = (const float*)d_in[1];
    const float* b0 = (const float*)d_in[2];
    const float* W1 = (const float*)d_in[3];
    const float* b1 = (const float*)d_in[4];
    const float* W2 = (const float*)d_in[5];
    const float* b2 = (const float*)d_in[6];
    const float* W3 = (const float*)d_in[7];
    const float* b3 = (const float*)d_in[8];
    const float* Wx = (const float*)d_in[9];
    const float* bx = (const float*)d_in[10];
    const float* Wy = (const float*)d_in[11];
    const float* by = (const float*)d_in[12];
    const float* Wz = (const float*)d_in[13];
    const float* bz = (const float*)d_in[14];
    const float* Z  = (const float*)d_in[15];
    const float* ew = (const float*)d_in[16];
    const int*   ei = (const int*)d_in[17];
    float* out = (float*)d_out;

    float* p = (float*)d_ws;
    float* h_a     = p; p += 8192;
    float* h_b     = p; p += 8192;
    float* hp      = p; p += 16 * 8192;        // MLP split partials
    float* coef    = p; p += 7056;
    float* cpart   = p; p += CS * 7056;
    float* deg     = p; p += 100000;
    int*   cnt     = (int*)p; p += 100000;
    int*   offs    = (int*)p; p += 100016;     // 100001 padded
    int*   pos     = (int*)p; p += 100000;
    int*   bsum    = (int*)p; p += 400;
    int*   bpre    = (int*)p; p += 400;
    int*   csr_src = (int*)p; p += 1600000;
    float* csr_w   = p; p += 1600000;
    float* fpart   = p; p += (size_t)FS * NN * 24;   // slot0 doubles as f0, slot1 as f1

    // ---- CSR build (independent of MLP) ----
    hipMemsetAsync(cnt, 0, NN * sizeof(int), stream);
    k_count<<<(EE + 255) / 256, 256, 0, stream>>>(ei, cnt);
    k_bsum<<<NB, 256, 0, stream>>>(cnt, bsum);
    k_bscan<<<1, 512, 0, stream>>>(bsum, bpre, offs);
    k_offs<<<NB, 256, 0, stream>>>(cnt, bpre, offs, pos);
    k_fill<<<(EE + 255) / 256, 256, 0, stream>>>(ei, ew, pos, csr_src, csr_w);
    k_degcsr<<<(NN + 255) / 256, 256, 0, stream>>>(offs, csr_w, deg);

    // ---- decode MLP (split-K) ----
    k_mlp_part<<<16 * 2, 256, 0, stream>>>(latent, W0, hp, LAT);
    k_mlp_comb<<<32, 256, 0, stream>>>(hp, 2, nullptr, b0, h_a);
    k_mlp_part<<<16 * 16, 256, 0, stream>>>(h_a, W1, hp, HH);
    k_mlp_comb<<<32, 256, 0, stream>>>(hp, 16, h_a, b1, h_b);
    k_mlp_part<<<16 * 16, 256, 0, stream>>>(h_b, W2, hp, HH);
    k_mlp_comb<<<32, 256, 0, stream>>>(hp, 16, h_b, b2, h_a);
    k_mlp_part<<<16 * 16, 256, 0, stream>>>(h_a, W3, hp, HH);
    k_mlp_comb<<<32, 256, 0, stream>>>(hp, 16, h_a, b3, h_b);
    k_coef_part<<<COB * CS, 256, 0, stream>>>(h_b, Wx, Wy, Wz, cpart);
    k_coef_comb<<<COB, 256, 0, stream>>>(cpart, bx, by, bz, coef);
    k_reg<<<1, 256, 0, stream>>>(coef, out + (size_t)BB * NN * 3);

    // ---- flow init (k-split) ----
    k_flow_part<<<NB * FS, 256, 0, stream>>>(coef, Z, fpart);
    k_flow_comb<<<(NN * 6 + 255) / 256, 256, 0, stream>>>(fpart);

    // ---- diffusion: 3 fused gather+combine steps ----
    float* f0 = fpart;
    float* f1 = fpart + (size_t)NN * 24;
    float* fc = f0;
    float* fo = f1;
    for (int s = 0; s < NSTEPS; ++s) {
        k_gather<<<(NN * 6 + 255) / 256, 256, 0, stream>>>(offs, csr_src, csr_w, deg, fc, fo);
        float* t = fc; fc = fo; fo = t;
    }

    k_out<<<(BB * NN * 3 + 255) / 256, 256, 0, stream>>>(fc, out);
}